// Round 1
// baseline (147.209 us; speedup 1.0000x reference)
//
#include <hip/hip_runtime.h>

typedef float f32x4 __attribute__((ext_vector_type(4)));
typedef unsigned short u16x8 __attribute__((ext_vector_type(8)));
typedef __bf16 bf16x8 __attribute__((ext_vector_type(8)));

static __device__ __forceinline__ unsigned short f32_to_bf16_rne(float f) {
    unsigned u = __builtin_bit_cast(unsigned, f);
    unsigned r = u + 0x7fffu + ((u >> 16) & 1u);
    return (unsigned short)(r >> 16);
}

// ---------------------------------------------------------------------------
// Kernel 1: convert + transpose the three W matrices (fp32 [256][512]) into
// bf16 W^T laid out [role][512 n][256 k] in workspace. 1.5 MB total -> trivial.
// ---------------------------------------------------------------------------
__global__ __launch_bounds__(256) void convert_w_kernel(
    const float* __restrict__ Wt_, const float* __restrict__ Wi_,
    const float* __restrict__ Wo_, unsigned short* __restrict__ out)
{
    int idx = blockIdx.x * 256 + threadIdx.x;   // [0, 3*512*256)
    int k = idx & 255;
    int n = (idx >> 8) & 511;
    int role = idx >> 17;
    const float* W = (role == 0) ? Wt_ : ((role == 1) ? Wi_ : Wo_);
    out[idx] = f32_to_bf16_rne(W[k * 512 + n]);
}

// ---------------------------------------------------------------------------
// Kernel 2: role-selected GEMM. Block = 64 rows (one t, role-uniform) x all
// 512 cols. 512 threads = 8 waves, each wave owns a 64x64 output tile.
// A (fp32) staged -> bf16 in XOR-swizzled LDS; B^T (bf16) read from L2.
// MFMA operands swapped so the epilogue stores float4 per lane.
// ---------------------------------------------------------------------------
__global__ __launch_bounds__(512, 4) void role_proj_kernel(
    const float* __restrict__ A,            // [131072][256] fp32
    const int* __restrict__ tmask,          // [64]
    const int* __restrict__ imask,          // [64]
    const unsigned short* __restrict__ Wws, // [3][512][256] bf16 (W^T)
    const float* __restrict__ bt, const float* __restrict__ bi,
    const float* __restrict__ bo,
    float* __restrict__ C)                  // [131072][512] fp32
{
    __shared__ unsigned short As[64 * 256];  // 32 KB, swizzled bf16 A tile

    const int tid = threadIdx.x;
    const int m0  = blockIdx.x * 64;

    // --- role selection (uniform per block: mask index = t/32 = blockIdx/32)
    const int mi = blockIdx.x >> 5;
    const int tv = tmask[mi];
    const int iv = imask[mi];
    const int role = tv ? 0 : (iv ? 1 : 2);
    const unsigned short* __restrict__ W = Wws + role * (512 * 256);
    const float* __restrict__ bias = (role == 0) ? bt : ((role == 1) ? bi : bo);

    // --- stage A tile: 64 rows x 256 k, fp32 -> bf16, swizzled LDS
    // unit = 8 consecutive k (16B bf16). 2048 units, 4 per thread.
#pragma unroll
    for (int j = 0; j < 4; ++j) {
        int u    = tid + 512 * j;
        int row  = u >> 5;        // 0..63
        int slot = u & 31;        // 0..31 (8 bf16 each)
        const f32x4* src = (const f32x4*)(A + (size_t)(m0 + row) * 256 + slot * 8);
        f32x4 v0 = src[0];
        f32x4 v1 = src[1];
        u16x8 pk;
        pk[0] = f32_to_bf16_rne(v0[0]); pk[1] = f32_to_bf16_rne(v0[1]);
        pk[2] = f32_to_bf16_rne(v0[2]); pk[3] = f32_to_bf16_rne(v0[3]);
        pk[4] = f32_to_bf16_rne(v1[0]); pk[5] = f32_to_bf16_rne(v1[1]);
        pk[6] = f32_to_bf16_rne(v1[2]); pk[7] = f32_to_bf16_rne(v1[3]);
        *(u16x8*)&As[row * 256 + ((slot ^ (row & 7)) << 3)] = pk;
    }
    __syncthreads();

    const int lane = tid & 63;
    const int wid  = tid >> 6;     // 0..7, wave's 64-col strip
    const int l15  = lane & 15;
    const int l4   = lane >> 4;    // 0..3
    const int nbase = wid * 64;

    f32x4 acc[4][4] = {};          // [fm][fn], 64 VGPRs

#pragma unroll
    for (int ks = 0; ks < 8; ++ks) {   // K = 8 * 32
        u16x8 bfr[4];
        u16x8 afr[4];
#pragma unroll
        for (int fn = 0; fn < 4; ++fn) {
            const int n = nbase + fn * 16 + l15;
            bfr[fn] = *(const u16x8*)(W + (size_t)n * 256 + ks * 32 + l4 * 8);
        }
#pragma unroll
        for (int fm = 0; fm < 4; ++fm) {
            const int row  = fm * 16 + l15;
            const int slot = ks * 4 + l4;
            afr[fm] = *(const u16x8*)&As[row * 256 + ((slot ^ (row & 7)) << 3)];
        }
#pragma unroll
        for (int fm = 0; fm < 4; ++fm) {
#pragma unroll
            for (int fn = 0; fn < 4; ++fn) {
                // Swapped operands: D[r][c] -> r = out-channel (4 consecutive
                // per lane via reg idx), c = activation row. Enables float4 store.
                acc[fm][fn] = __builtin_amdgcn_mfma_f32_16x16x32_bf16(
                    __builtin_bit_cast(bf16x8, bfr[fn]),
                    __builtin_bit_cast(bf16x8, afr[fm]),
                    acc[fm][fn], 0, 0, 0);
            }
        }
    }

    // --- epilogue: bias + coalesced float4 stores
#pragma unroll
    for (int fn = 0; fn < 4; ++fn) {
        const int col = nbase + fn * 16 + l4 * 4;     // 4 consecutive channels
        const f32x4 bv = *(const f32x4*)(bias + col);
#pragma unroll
        for (int fm = 0; fm < 4; ++fm) {
            const int row = m0 + fm * 16 + l15;
            f32x4 v = acc[fm][fn] + bv;
            *(f32x4*)(C + (size_t)row * 512 + col) = v;
        }
    }
}

extern "C" void kernel_launch(void* const* d_in, const int* in_sizes, int n_in,
                              void* d_out, int out_size, void* d_ws, size_t ws_size,
                              hipStream_t stream) {
    const float* A   = (const float*)d_in[0];
    const int*   tm  = (const int*)d_in[1];
    const int*   im  = (const int*)d_in[2];
    const float* Wt_ = (const float*)d_in[3];
    const float* bt  = (const float*)d_in[4];
    const float* Wi_ = (const float*)d_in[5];
    const float* bi  = (const float*)d_in[6];
    const float* Wo_ = (const float*)d_in[7];
    const float* bo  = (const float*)d_in[8];

    unsigned short* Wws = (unsigned short*)d_ws;   // needs 3*512*256*2 = 768 KB

    hipLaunchKernelGGL(convert_w_kernel, dim3((3 * 512 * 256) / 256), dim3(256),
                       0, stream, Wt_, Wi_, Wo_, Wws);

    hipLaunchKernelGGL(role_proj_kernel, dim3(131072 / 64), dim3(512),
                       0, stream, A, tm, im, Wws, bt, bi, bo, (float*)d_out);
}

// Round 2
// 146.394 us; speedup vs baseline: 1.0056x; 1.0056x over previous
//
#include <hip/hip_runtime.h>

typedef float f32x4 __attribute__((ext_vector_type(4)));
typedef unsigned short u16x8 __attribute__((ext_vector_type(8)));
typedef __bf16 bf16x8 __attribute__((ext_vector_type(8)));

// ---------------------------------------------------------------------------
// Kernel 1: convert + transpose three W (fp32 [256 k][512 n]) into bf16 W^T
// [role][512 n][256 k] in workspace, via 64x64 LDS tile transpose.
// Grid: 3 roles x 4 k-tiles x 8 n-tiles = 96 blocks x 256 threads.
// ---------------------------------------------------------------------------
__global__ __launch_bounds__(256) void convert_w_kernel(
    const float* __restrict__ Wt_, const float* __restrict__ Wi_,
    const float* __restrict__ Wo_, unsigned short* __restrict__ out)
{
    __shared__ unsigned short tile[64][72];   // 72 = 16B-aligned rows, bank-spread

    const int b    = blockIdx.x;
    const int role = b >> 5;
    const int kt   = (b & 31) >> 3;   // 0..3  (k tile of 64)
    const int nt   = b & 7;           // 0..7  (n tile of 64)
    const float* __restrict__ W = (role == 0) ? Wt_ : ((role == 1) ? Wi_ : Wo_);

    const int t  = threadIdx.x;
    const int r0 = t >> 4;            // 0..15
    const int c4 = (t & 15) << 2;     // 0..60

#pragma unroll
    for (int j = 0; j < 4; ++j) {
        const int kl = r0 + j * 16;   // local k 0..63
        f32x4 v = *(const f32x4*)(W + (size_t)(kt * 64 + kl) * 512 + nt * 64 + c4);
#pragma unroll
        for (int e = 0; e < 4; ++e)
            tile[c4 + e][kl] = __builtin_bit_cast(unsigned short, (__bf16)v[e]);
    }
    __syncthreads();

    const int cs = t & 7;             // 0..7 (8 u16 each)
#pragma unroll
    for (int p = 0; p < 2; ++p) {
        const int r = (t >> 3) + p * 32;          // local n 0..63
        u16x8 v = *(const u16x8*)&tile[r][cs * 8];
        *(u16x8*)(out + (size_t)role * 512 * 256 +
                  (size_t)(nt * 64 + r) * 256 + kt * 64 + cs * 8) = v;
    }
}

// ---------------------------------------------------------------------------
// Kernel 2: role-selected GEMM. Block = 64 rows (one t, role-uniform) x 512
// cols. 512 threads = 8 waves, each wave a 64x64 output tile.
// A fp32 -> bf16 staged in XOR-swizzled LDS (nontemporal loads);
// B^T bf16 from L2 with 1-deep software prefetch; nontemporal C stores.
// ---------------------------------------------------------------------------
__global__ __launch_bounds__(512, 4) void role_proj_kernel(
    const float* __restrict__ A,            // [131072][256] fp32
    const int* __restrict__ tmask,          // [64]
    const int* __restrict__ imask,          // [64]
    const unsigned short* __restrict__ Wws, // [3][512][256] bf16 (W^T)
    const float* __restrict__ bt, const float* __restrict__ bi,
    const float* __restrict__ bo,
    float* __restrict__ C)                  // [131072][512] fp32
{
    __shared__ unsigned short As[64 * 256];  // 32 KB swizzled bf16 A tile

    const int tid = threadIdx.x;
    const int m0  = blockIdx.x * 64;

    // role is uniform per block: mask index = t/32 = blockIdx/32
    const int mi = blockIdx.x >> 5;
    const int role = tmask[mi] ? 0 : (imask[mi] ? 1 : 2);
    const unsigned short* __restrict__ W = Wws + (size_t)role * (512 * 256);
    const float* __restrict__ bias = (role == 0) ? bt : ((role == 1) ? bi : bo);

    // --- stage A tile: 64 rows x 256 k, fp32 -> bf16, swizzled LDS
#pragma unroll
    for (int j = 0; j < 4; ++j) {
        const int u    = tid + 512 * j;
        const int row  = u >> 5;        // 0..63
        const int slot = u & 31;        // 0..31 (8 bf16 each)
        const f32x4* src = (const f32x4*)(A + (size_t)(m0 + row) * 256 + slot * 8);
        f32x4 v0 = __builtin_nontemporal_load(src);
        f32x4 v1 = __builtin_nontemporal_load(src + 1);
        bf16x8 pk;
        pk[0] = (__bf16)v0[0]; pk[1] = (__bf16)v0[1];
        pk[2] = (__bf16)v0[2]; pk[3] = (__bf16)v0[3];
        pk[4] = (__bf16)v1[0]; pk[5] = (__bf16)v1[1];
        pk[6] = (__bf16)v1[2]; pk[7] = (__bf16)v1[3];
        *(bf16x8*)&As[row * 256 + ((slot ^ (row & 7)) << 3)] = pk;
    }
    __syncthreads();

    const int lane  = tid & 63;
    const int wid   = tid >> 6;     // 0..7: wave's 64-col strip
    const int l15   = lane & 15;
    const int l4    = lane >> 4;    // 0..3
    const int nbase = wid * 64;
    const int r7    = l15 & 7;      // LDS swizzle key (row&7 == l15&7)

    // per-fn W fragment base pointers (n = nbase+fn*16+l15, k = l4*8)
    const unsigned short* wp0 = W + (size_t)(nbase +  0 + l15) * 256 + l4 * 8;
    const unsigned short* wp1 = W + (size_t)(nbase + 16 + l15) * 256 + l4 * 8;
    const unsigned short* wp2 = W + (size_t)(nbase + 32 + l15) * 256 + l4 * 8;
    const unsigned short* wp3 = W + (size_t)(nbase + 48 + l15) * 256 + l4 * 8;

    f32x4 acc[4][4] = {};          // [fm][fn], 64 VGPRs

    u16x8 bcur[4];
    bcur[0] = *(const u16x8*)wp0;
    bcur[1] = *(const u16x8*)wp1;
    bcur[2] = *(const u16x8*)wp2;
    bcur[3] = *(const u16x8*)wp3;

#pragma unroll 1
    for (int ks = 0; ks < 8; ++ks) {
        // A fragments for this k-slice (ds_read_b128, 2-way conflicts = free)
        u16x8 afr[4];
#pragma unroll
        for (int fm = 0; fm < 4; ++fm) {
            const int row  = fm * 16 + l15;
            const int slot = (ks * 4 + l4) ^ r7;
            afr[fm] = *(const u16x8*)&As[row * 256 + slot * 8];
        }
        // prefetch next k-slice's B fragments (1-deep pipeline)
        u16x8 bnxt[4];
        if (ks < 7) {
            const int o = (ks + 1) * 32;
            bnxt[0] = *(const u16x8*)(wp0 + o);
            bnxt[1] = *(const u16x8*)(wp1 + o);
            bnxt[2] = *(const u16x8*)(wp2 + o);
            bnxt[3] = *(const u16x8*)(wp3 + o);
        }
#pragma unroll
        for (int fm = 0; fm < 4; ++fm) {
#pragma unroll
            for (int fn = 0; fn < 4; ++fn) {
                // swapped operands: acc row = out-channel (4 consecutive per
                // lane via reg idx), col = activation row -> float4 C stores
                acc[fm][fn] = __builtin_amdgcn_mfma_f32_16x16x32_bf16(
                    __builtin_bit_cast(bf16x8, bcur[fn]),
                    __builtin_bit_cast(bf16x8, afr[fm]),
                    acc[fm][fn], 0, 0, 0);
            }
        }
#pragma unroll
        for (int fn = 0; fn < 4; ++fn) bcur[fn] = bnxt[fn];
    }

    // --- epilogue: bias + nontemporal float4 stores (C never re-read)
#pragma unroll
    for (int fn = 0; fn < 4; ++fn) {
        const int col = nbase + fn * 16 + l4 * 4;     // 4 consecutive channels
        const f32x4 bv = *(const f32x4*)(bias + col);
#pragma unroll
        for (int fm = 0; fm < 4; ++fm) {
            const int row = m0 + fm * 16 + l15;
            f32x4 v = acc[fm][fn] + bv;
            __builtin_nontemporal_store(v, (f32x4*)(C + (size_t)row * 512 + col));
        }
    }
}

extern "C" void kernel_launch(void* const* d_in, const int* in_sizes, int n_in,
                              void* d_out, int out_size, void* d_ws, size_t ws_size,
                              hipStream_t stream) {
    const float* A   = (const float*)d_in[0];
    const int*   tm  = (const int*)d_in[1];
    const int*   im  = (const int*)d_in[2];
    const float* Wt_ = (const float*)d_in[3];
    const float* bt  = (const float*)d_in[4];
    const float* Wi_ = (const float*)d_in[5];
    const float* bi  = (const float*)d_in[6];
    const float* Wo_ = (const float*)d_in[7];
    const float* bo  = (const float*)d_in[8];

    unsigned short* Wws = (unsigned short*)d_ws;   // 3*512*256*2 = 768 KB

    hipLaunchKernelGGL(convert_w_kernel, dim3(96), dim3(256),
                       0, stream, Wt_, Wi_, Wo_, Wws);

    hipLaunchKernelGGL(role_proj_kernel, dim3(131072 / 64), dim3(512),
                       0, stream, A, tm, im, Wws, bt, bi, bo, (float*)d_out);
}

// Round 3
// 136.862 us; speedup vs baseline: 1.0756x; 1.0696x over previous
//
#include <hip/hip_runtime.h>

typedef float f32x4 __attribute__((ext_vector_type(4)));
typedef unsigned short u16x8 __attribute__((ext_vector_type(8)));
typedef __bf16 bf16x8 __attribute__((ext_vector_type(8)));

// ---------------------------------------------------------------------------
// Kernel 1: convert + transpose three W (fp32 [256 k][512 n]) into bf16 W^T
// [role][512 n][256 k] in workspace, via 64x64 LDS tile transpose.
// ---------------------------------------------------------------------------
__global__ __launch_bounds__(256) void convert_w_kernel(
    const float* __restrict__ Wt_, const float* __restrict__ Wi_,
    const float* __restrict__ Wo_, unsigned short* __restrict__ out)
{
    __shared__ unsigned short tile[64][72];

    const int b    = blockIdx.x;
    const int role = b >> 5;
    const int kt   = (b & 31) >> 3;
    const int nt   = b & 7;
    const float* __restrict__ W = (role == 0) ? Wt_ : ((role == 1) ? Wi_ : Wo_);

    const int t  = threadIdx.x;
    const int r0 = t >> 4;
    const int c4 = (t & 15) << 2;

#pragma unroll
    for (int j = 0; j < 4; ++j) {
        const int kl = r0 + j * 16;
        f32x4 v = *(const f32x4*)(W + (size_t)(kt * 64 + kl) * 512 + nt * 64 + c4);
#pragma unroll
        for (int e = 0; e < 4; ++e)
            tile[c4 + e][kl] = __builtin_bit_cast(unsigned short, (__bf16)v[e]);
    }
    __syncthreads();

    const int cs = t & 7;
#pragma unroll
    for (int p = 0; p < 2; ++p) {
        const int r = (t >> 3) + p * 32;
        u16x8 v = *(const u16x8*)&tile[r][cs * 8];
        *(u16x8*)(out + (size_t)role * 512 * 256 +
                  (size_t)(nt * 64 + r) * 256 + kt * 64 + cs * 8) = v;
    }
}

// ---------------------------------------------------------------------------
// Kernel 2: persistent role-selected GEMM, software-pipelined.
// Grid = 256 blocks (1/CU), 512 threads (8 waves). Each block owns 8
// contiguous 64-row tiles (role uniform: 8 | 32). LDS double-buffered A
// (fp32->bf16, XOR-swizzled). Per iteration: issue next tile's A loads ->
// compute current from LDS (B 1-deep prefetch from L2) -> nontemporal C
// stores -> convert+ds_write next buffer -> one barrier. The compiler's
// auto-waitcnt before the convert waits only on the A loads (counted),
// so stores stay in flight.
// ---------------------------------------------------------------------------
__global__ __launch_bounds__(512, 2) void role_proj_kernel(
    const float* __restrict__ A,            // [131072][256] fp32
    const int* __restrict__ tmask,          // [64]
    const int* __restrict__ imask,          // [64]
    const unsigned short* __restrict__ Wws, // [3][512][256] bf16 (W^T)
    const float* __restrict__ bt, const float* __restrict__ bi,
    const float* __restrict__ bo,
    float* __restrict__ C)                  // [131072][512] fp32
{
    __shared__ unsigned short As[2][64 * 256];   // 2 x 32 KB

    const int tid = threadIdx.x;
    const int t0  = blockIdx.x * 8;              // first tile index
    const int mi  = t0 >> 5;                     // role uniform over 8 tiles
    const int role = tmask[mi] ? 0 : (imask[mi] ? 1 : 2);
    const unsigned short* __restrict__ W = Wws + (size_t)role * (512 * 256);
    const float* __restrict__ bias = (role == 0) ? bt : ((role == 1) ? bi : bo);

    // --- staging geometry: per thread slot fixed, rows r0 + 16j
    const int r0   = tid >> 5;                   // 0..15
    const int sl   = tid & 31;                   // 0..31 (8 k each)
    const int swsl = (sl ^ (r0 & 7)) << 3;       // swizzled u16 offset (row&7==r0&7)
    const float* aptr = A + (size_t)t0 * 16384 + (size_t)r0 * 256 + sl * 8;

    // --- compute geometry
    const int lane  = tid & 63;
    const int wid   = tid >> 6;
    const int l15   = lane & 15;
    const int l4    = lane >> 4;
    const int nbase = wid * 64;
    const int r7    = l15 & 7;

    const unsigned short* wp0 = W + (size_t)(nbase +  0 + l15) * 256 + l4 * 8;
    const unsigned short* wp1 = W + (size_t)(nbase + 16 + l15) * 256 + l4 * 8;
    const unsigned short* wp2 = W + (size_t)(nbase + 32 + l15) * 256 + l4 * 8;
    const unsigned short* wp3 = W + (size_t)(nbase + 48 + l15) * 256 + l4 * 8;

    // bias hoisted (constant per block)
    f32x4 bv[4];
#pragma unroll
    for (int fn = 0; fn < 4; ++fn)
        bv[fn] = *(const f32x4*)(bias + nbase + fn * 16 + l4 * 4);

    f32x4 ld[4][2];

    // --- prologue: stage tile 0 into buf 0
#pragma unroll
    for (int j = 0; j < 4; ++j) {
        const f32x4* src = (const f32x4*)(aptr + j * (16 * 256));
        ld[j][0] = __builtin_nontemporal_load(src);
        ld[j][1] = __builtin_nontemporal_load(src + 1);
    }
#pragma unroll
    for (int j = 0; j < 4; ++j) {
        bf16x8 pk;
        pk[0] = (__bf16)ld[j][0][0]; pk[1] = (__bf16)ld[j][0][1];
        pk[2] = (__bf16)ld[j][0][2]; pk[3] = (__bf16)ld[j][0][3];
        pk[4] = (__bf16)ld[j][1][0]; pk[5] = (__bf16)ld[j][1][1];
        pk[6] = (__bf16)ld[j][1][2]; pk[7] = (__bf16)ld[j][1][3];
        *(bf16x8*)&As[0][(r0 + 16 * j) * 256 + swsl] = pk;
    }
    __syncthreads();

#pragma unroll 1
    for (int it = 0; it < 8; ++it) {
        const int cur = it & 1;

        // issue next tile's A loads (latency hides under compute + stores)
        if (it < 7) {
#pragma unroll
            for (int j = 0; j < 4; ++j) {
                const f32x4* src =
                    (const f32x4*)(aptr + (size_t)(it + 1) * 16384 + j * (16 * 256));
                ld[j][0] = __builtin_nontemporal_load(src);
                ld[j][1] = __builtin_nontemporal_load(src + 1);
            }
        }

        // --- compute tile `it` from As[cur]
        f32x4 acc[4][4] = {};
        u16x8 bcur[4];
        bcur[0] = *(const u16x8*)wp0;
        bcur[1] = *(const u16x8*)wp1;
        bcur[2] = *(const u16x8*)wp2;
        bcur[3] = *(const u16x8*)wp3;

#pragma unroll 1
        for (int ks = 0; ks < 8; ++ks) {
            u16x8 afr[4];
#pragma unroll
            for (int fm = 0; fm < 4; ++fm) {
                const int row  = fm * 16 + l15;
                const int slot = (ks * 4 + l4) ^ r7;
                afr[fm] = *(const u16x8*)&As[cur][row * 256 + slot * 8];
            }
            u16x8 bnxt[4];
            if (ks < 7) {
                const int o = (ks + 1) * 32;
                bnxt[0] = *(const u16x8*)(wp0 + o);
                bnxt[1] = *(const u16x8*)(wp1 + o);
                bnxt[2] = *(const u16x8*)(wp2 + o);
                bnxt[3] = *(const u16x8*)(wp3 + o);
            }
#pragma unroll
            for (int fm = 0; fm < 4; ++fm) {
#pragma unroll
                for (int fn = 0; fn < 4; ++fn) {
                    acc[fm][fn] = __builtin_amdgcn_mfma_f32_16x16x32_bf16(
                        __builtin_bit_cast(bf16x8, bcur[fn]),
                        __builtin_bit_cast(bf16x8, afr[fm]),
                        acc[fm][fn], 0, 0, 0);
                }
            }
#pragma unroll
            for (int fn = 0; fn < 4; ++fn) bcur[fn] = bnxt[fn];
        }

        // --- epilogue: bias + nontemporal float4 stores (fire and forget)
        const int m0 = (t0 + it) * 64;
#pragma unroll
        for (int fn = 0; fn < 4; ++fn) {
            const int col = nbase + fn * 16 + l4 * 4;
#pragma unroll
            for (int fm = 0; fm < 4; ++fm) {
                f32x4 v = acc[fm][fn] + bv[fn];
                __builtin_nontemporal_store(
                    v, (f32x4*)(C + (size_t)(m0 + fm * 16 + l15) * 512 + col));
            }
        }

        // --- convert + write next tile into the other buffer
        if (it < 7) {
#pragma unroll
            for (int j = 0; j < 4; ++j) {
                bf16x8 pk;
                pk[0] = (__bf16)ld[j][0][0]; pk[1] = (__bf16)ld[j][0][1];
                pk[2] = (__bf16)ld[j][0][2]; pk[3] = (__bf16)ld[j][0][3];
                pk[4] = (__bf16)ld[j][1][0]; pk[5] = (__bf16)ld[j][1][1];
                pk[6] = (__bf16)ld[j][1][2]; pk[7] = (__bf16)ld[j][1][3];
                *(bf16x8*)&As[cur ^ 1][(r0 + 16 * j) * 256 + swsl] = pk;
            }
        }
        __syncthreads();
    }
}

extern "C" void kernel_launch(void* const* d_in, const int* in_sizes, int n_in,
                              void* d_out, int out_size, void* d_ws, size_t ws_size,
                              hipStream_t stream) {
    const float* A   = (const float*)d_in[0];
    const int*   tm  = (const int*)d_in[1];
    const int*   im  = (const int*)d_in[2];
    const float* Wt_ = (const float*)d_in[3];
    const float* bt  = (const float*)d_in[4];
    const float* Wi_ = (const float*)d_in[5];
    const float* bi  = (const float*)d_in[6];
    const float* Wo_ = (const float*)d_in[7];
    const float* bo  = (const float*)d_in[8];

    unsigned short* Wws = (unsigned short*)d_ws;   // 3*512*256*2 = 768 KB

    hipLaunchKernelGGL(convert_w_kernel, dim3(96), dim3(256),
                       0, stream, Wt_, Wi_, Wo_, Wws);

    hipLaunchKernelGGL(role_proj_kernel, dim3(256), dim3(512),
                       0, stream, A, tm, im, Wws, bt, bi, bo, (float*)d_out);
}